// Round 9
// baseline (460.610 us; speedup 1.0000x reference)
//
#include <hip/hip_runtime.h>

// Problem dims (fixed by setup_inputs): T=1024, B=8, d=64, n=64
#define T_DIM 1024
#define B_DIM 8
#define D_DIM 64
#define N_DIM 64

typedef float v4f __attribute__((ext_vector_type(4)));

// 64 chunks of 16 timesteps; task = (c, b, dt) -> 64*8*4 = 2048 tasks
#define C_CHUNKS 64
#define C_LEN 16
#define NTASK (C_CHUNKS * B_DIM * 4)
#define SLAB (B_DIM * D_DIM * N_DIM)  // 32768 floats per chunk slab

// Workspace layout (floats):
//   psum : [64][B][D][N] at 0         (2097152 floats, 8 MB)
//   lsum : [B][64][N]    at 2097152   (32768 floats)
//   bar  : barrier counters at 2129920 (64 groups x 32-uint spacing + root + gen)
#define WS_PSUM 0
#define WS_LSUM (C_CHUNKS * SLAB)
#define WS_BAR (WS_LSUM + B_DIM * C_CHUNKS * N_DIM)
#define BAR_UINTS (64 * 32 + 2)

// ---------------------------------------------------------------------------
// K1: per-(b, t-chunk) sums of log(max(alpha,1e-8)).
// Block = (b,c), 256 threads = (q = tid>>6, n = tid&63): 4 logs each + reduce.
// ---------------------------------------------------------------------------
__global__ __launch_bounds__(256) void lsum_kernel(
    const float* __restrict__ alpha, float* __restrict__ lsum) {
  __shared__ float qs[4][N_DIM];
  const int b = blockIdx.x >> 6;
  const int c = blockIdx.x & 63;
  const int tid = threadIdx.x;
  const int q = tid >> 6, n = tid & 63;

  float s = 0.f;
#pragma unroll
  for (int i = 0; i < 4; ++i) {
    const int t = c * C_LEN + q * 4 + i;
    s += __logf(fmaxf(alpha[((size_t)t * B_DIM + b) * N_DIM + n], 1e-8f));
  }
  qs[q][n] = s;
  __syncthreads();
  if (tid < 64) {
    lsum[((size_t)b * C_CHUNKS + c) * N_DIM + tid] =
        (qs[0][tid] + qs[1][tid]) + (qs[2][tid] + qs[3][tid]);
  }
}

// ---------------------------------------------------------------------------
// Hierarchical device-scope grid barrier. One arrival per block (thread 0).
// 64 group counters on separate cache lines -> root -> generation flag.
// All blocks are co-resident (grid <= 8 blocks/CU enforced by launch bounds
// and host-side grid sizing), so spinning cannot deadlock.
// ---------------------------------------------------------------------------
__device__ __forceinline__ void grid_barrier(unsigned* bar, unsigned nblk) {
  __syncthreads();
  if (threadIdx.x == 0) {
    __threadfence();  // release prior global writes (device scope)
    unsigned* groups = bar;
    unsigned* root = bar + 64 * 32;
    unsigned* gen = root + 1;
    const unsigned g =
        __hip_atomic_load(gen, __ATOMIC_RELAXED, __HIP_MEMORY_SCOPE_AGENT);
    const unsigned gid = blockIdx.x & 63;
    const unsigned gtarget = ((nblk - 1 - gid) >> 6) + 1;  // blocks in my group
    const unsigned ngroups = (nblk < 64) ? nblk : 64;
    const unsigned a = __hip_atomic_fetch_add(
        groups + gid * 32, 1u, __ATOMIC_ACQ_REL, __HIP_MEMORY_SCOPE_AGENT);
    if (a + 1 == gtarget) {
      __hip_atomic_store(groups + gid * 32, 0u, __ATOMIC_RELAXED,
                         __HIP_MEMORY_SCOPE_AGENT);
      const unsigned r = __hip_atomic_fetch_add(
          root, 1u, __ATOMIC_ACQ_REL, __HIP_MEMORY_SCOPE_AGENT);
      if (r + 1 == ngroups) {
        __hip_atomic_store(root, 0u, __ATOMIC_RELAXED, __HIP_MEMORY_SCOPE_AGENT);
        __hip_atomic_store(gen, g + 1u, __ATOMIC_RELEASE,
                           __HIP_MEMORY_SCOPE_AGENT);
      }
    }
    while (__hip_atomic_load(gen, __ATOMIC_ACQUIRE, __HIP_MEMORY_SCOPE_AGENT) ==
           g) {
      __builtin_amdgcn_s_sleep(4);
    }
    __threadfence();  // acquire: make other blocks' writes visible
  }
  __syncthreads();
}

// ---------------------------------------------------------------------------
// Staging: per-task (c,b,dt) compute w_t[16][64] and v_t[16][16] into LDS.
// All 256 threads participate: thread (q = tid>>6, n = tid&63) handles
// t-steps q*4..q*4+3 of the decay chain (LDS exchange of quarter log-sums).
// ---------------------------------------------------------------------------
__device__ __forceinline__ void stage_tiles(
    int b, int c, int dt, int tid, const float* __restrict__ v,
    const float* __restrict__ alpha, const float* __restrict__ kk,
    const float* __restrict__ lsum, float (*w_t)[N_DIM], float (*v_t)[16],
    float (*qs)[N_DIM]) {
  const int q = tid >> 6;
  const int n = tid & 63;

  // chunk-level exclusive prefix + grand total of per-chunk log-sums
  const float* __restrict__ lp = lsum + (size_t)b * C_CHUNKS * N_DIM + n;
  float pre = 0.f, tot = 0.f;
#pragma unroll 8
  for (int j = 0; j < C_CHUNKS; ++j) {
    const float sj = lp[(size_t)j * N_DIM];
    tot += sj;
    pre += (j < c) ? sj : 0.f;
  }
  // Matches reference f32 numerics: exp(tot) underflows to 0 -> denom = 1e-8
  const float invden = 1.0f / (__expf(tot) + 1e-8f);

  // in-chunk quarter log-sums
  float la[4];
  float qsum = 0.f;
#pragma unroll
  for (int i = 0; i < 4; ++i) {
    const int t = c * C_LEN + q * 4 + i;
    la[i] = __logf(fmaxf(alpha[((size_t)t * B_DIM + b) * N_DIM + n], 1e-8f));
    qsum += la[i];
  }
  qs[q][n] = qsum;

  // v-tile: one element per thread (vi = t-step, dl = d_loc)
  {
    const int vi = tid >> 4, dl = tid & 15;
    v_t[vi][dl] =
        v[((size_t)(c * C_LEN + vi) * B_DIM + b) * D_DIM + dt * 16 + dl];
  }
  __syncthreads();

  float cum = pre;
#pragma unroll
  for (int q2 = 0; q2 < 3; ++q2)
    if (q2 < q) cum += qs[q2][n];
#pragma unroll
  for (int i = 0; i < 4; ++i) {
    const int t = c * C_LEN + q * 4 + i;
    cum += la[i];
    w_t[q * 4 + i][n] =
        kk[((size_t)t * B_DIM + b) * N_DIM + n] * __expf(cum) * invden;
  }
  __syncthreads();
}

// ---------------------------------------------------------------------------
// K2: phase A (stage + psum write) -> grid barrier -> phase B (prefix gather
// from psum + 16-step FMA/store, reusing live LDS tiles when grid == NTASK).
// ---------------------------------------------------------------------------
__global__ __launch_bounds__(256, 8) void mega_kernel(
    const float* __restrict__ v, const float* __restrict__ alpha,
    const float* __restrict__ kk, float* __restrict__ ws,
    float* __restrict__ out) {
  __shared__ float w_t[C_LEN][N_DIM];
  __shared__ float v_t[C_LEN][16];
  __shared__ float qs[4][N_DIM];

  const int tid = threadIdx.x;
  const unsigned nblk = gridDim.x;
  const float* lsum = ws + WS_LSUM;
  unsigned* bar = (unsigned*)(ws + WS_BAR);
  const int dl = tid >> 4;
  const int n0 = (tid & 15) * 4;

  // ---- phase A: stage tiles, compute per-chunk psum ----
  for (unsigned task = blockIdx.x; task < NTASK; task += nblk) {
    const int dt = task & 3, b = (task >> 2) & 7, c = task >> 5;
    stage_tiles(b, c, dt, tid, v, alpha, kk, lsum, w_t, v_t, qs);
    v4f acc = {0.f, 0.f, 0.f, 0.f};
#pragma unroll
    for (int i = 0; i < C_LEN; ++i) {
      const float vv = v_t[i][dl];
      const v4f w4 = *(const v4f*)&w_t[i][n0];
      acc.x = fmaf(vv, w4.x, acc.x);
      acc.y = fmaf(vv, w4.y, acc.y);
      acc.z = fmaf(vv, w4.z, acc.z);
      acc.w = fmaf(vv, w4.w, acc.w);
    }
    *(v4f*)(ws + WS_PSUM +
            (((size_t)c * B_DIM + b) * D_DIM + dt * 16 + dl) * N_DIM + n0) = acc;
    __syncthreads();  // tile reuse guard (no-op cost when single-trip)
  }

  grid_barrier(bar, nblk);

  // ---- phase B: per-column prefix gather + scan store ----
  const bool tiles_live = (nblk >= NTASK);
  for (unsigned task = blockIdx.x; task < NTASK; task += nblk) {
    const int dt = task & 3, b = (task >> 2) & 7, c = task >> 5;
    if (!tiles_live) stage_tiles(b, c, dt, tid, v, alpha, kk, lsum, w_t, v_t, qs);
    const int d = dt * 16 + dl;

    v4f acc = {0.f, 0.f, 0.f, 0.f};
    const float* __restrict__ pp =
        ws + WS_PSUM + ((size_t)b * D_DIM + d) * N_DIM + n0;
#pragma unroll 4
    for (int j = 0; j < c; ++j) {
      const v4f p = *(const v4f*)(pp + (size_t)j * SLAB);
      acc.x += p.x; acc.y += p.y; acc.z += p.z; acc.w += p.w;
    }
#pragma unroll
    for (int i = 0; i < C_LEN; ++i) {
      const int t = c * C_LEN + i;
      const float vv = v_t[i][dl];
      const v4f w4 = *(const v4f*)&w_t[i][n0];
      acc.x = fmaf(vv, w4.x, acc.x);
      acc.y = fmaf(vv, w4.y, acc.y);
      acc.z = fmaf(vv, w4.z, acc.z);
      acc.w = fmaf(vv, w4.w, acc.w);
      *(v4f*)(out + (((size_t)t * B_DIM + b) * D_DIM + d) * N_DIM + n0) = acc;
    }
    __syncthreads();
  }
}

// ---------------------------------------------------------------------------
extern "C" void kernel_launch(void* const* d_in, const int* in_sizes, int n_in,
                              void* d_out, int out_size, void* d_ws, size_t ws_size,
                              hipStream_t stream) {
  const float* v     = (const float*)d_in[0];
  const float* k     = (const float*)d_in[1];
  const float* alpha = (const float*)d_in[2];
  float* out = (float*)d_out;
  float* ws  = (float*)d_ws;  // uses ~8.6 MB

  // Grid sized so all blocks are co-resident: 8 blocks/CU guaranteed by
  // __launch_bounds__(256, 8) (64 VGPR cap, 6 KB LDS).
  int dev = 0, cus = 0;
  if (hipGetDevice(&dev) != hipSuccess) dev = 0;
  if (hipDeviceGetAttribute(&cus, hipDeviceAttributeMultiprocessorCount, dev) !=
          hipSuccess ||
      cus <= 0) {
    cus = 256;
  }
  unsigned nblk = (unsigned)cus * 8u;
  if (nblk > NTASK) nblk = NTASK;
  if (nblk == 0) nblk = 1;

  // Zero barrier counters (capture-safe async memset).
  (void)hipMemsetAsync((void*)(ws + WS_BAR), 0, BAR_UINTS * sizeof(unsigned),
                       stream);

  lsum_kernel<<<B_DIM * C_CHUNKS, 256, 0, stream>>>(alpha, ws + WS_LSUM);
  mega_kernel<<<nblk, 256, 0, stream>>>(v, alpha, k, ws, out);
}

// Round 10
// 156.488 us; speedup vs baseline: 2.9434x; 2.9434x over previous
//
#include <hip/hip_runtime.h>

// Problem dims (fixed by setup_inputs): T=1024, B=8, d=64, n=64
#define T_DIM 1024
#define B_DIM 8
#define D_DIM 64
#define N_DIM 64

typedef float v4f __attribute__((ext_vector_type(4)));

// 64 chunks of 16 timesteps
#define C_CHUNKS 64
#define C_LEN 16
#define SLAB (B_DIM * D_DIM * N_DIM)  // 32768 floats per chunk slab

// Workspace layout (floats):
//   w    : [T][B][N]     at 0          (524288 floats, 2 MB)
//   psum : [64][B][D][N] at 524288     (2097152 floats, 8 MB)
//   lsum : [B][64][N]    at 2621440    (32768 floats)
#define WS_W 0
#define WS_PSUM (T_DIM * B_DIM * N_DIM)
#define WS_LSUM (WS_PSUM + C_CHUNKS * SLAB)

// ---------------------------------------------------------------------------
// K1: per-(b, t-chunk) sums of log(max(alpha,1e-8)).
// Block = (b,c), 256 threads = (q = tid>>6, n = tid&63): 4 logs each + reduce.
// 512 blocks x 256 thr = 8 waves/CU.
// ---------------------------------------------------------------------------
__global__ __launch_bounds__(256) void lsum_kernel(
    const float* __restrict__ alpha, float* __restrict__ lsum) {
  __shared__ float qs[4][N_DIM];
  const int b = blockIdx.x >> 6;
  const int c = blockIdx.x & 63;
  const int tid = threadIdx.x;
  const int q = tid >> 6, n = tid & 63;

  float s = 0.f;
#pragma unroll
  for (int i = 0; i < 4; ++i) {
    const int t = c * C_LEN + q * 4 + i;
    s += __logf(fmaxf(alpha[((size_t)t * B_DIM + b) * N_DIM + n], 1e-8f));
  }
  qs[q][n] = s;
  __syncthreads();
  if (tid < 64) {
    lsum[((size_t)b * C_CHUNKS + c) * N_DIM + tid] =
        (qs[0][tid] + qs[1][tid]) + (qs[2][tid] + qs[3][tid]);
  }
}

// ---------------------------------------------------------------------------
// K2: emit w[t,b,n] = k * expf(prefix_log) / (expf(total_log)+1e-8).
// Block = (b,c), 256 threads; the 16-step chain is split across 4 thread
// quarters using LDS quarter log-sums. 8 waves/CU, fast-math transcendentals.
// ---------------------------------------------------------------------------
__global__ __launch_bounds__(256) void w_emit_kernel(
    const float* __restrict__ alpha, const float* __restrict__ kk,
    const float* __restrict__ lsum, float* __restrict__ w) {
  __shared__ float qs[4][N_DIM];
  const int b = blockIdx.x >> 6;
  const int c = blockIdx.x & 63;
  const int tid = threadIdx.x;
  const int q = tid >> 6, n = tid & 63;

  // chunk-level exclusive prefix + grand total of per-chunk log-sums
  const float* __restrict__ lp = lsum + (size_t)b * C_CHUNKS * N_DIM + n;
  float pre = 0.f, tot = 0.f;
#pragma unroll 8
  for (int j = 0; j < C_CHUNKS; ++j) {
    const float sj = lp[(size_t)j * N_DIM];
    tot += sj;
    pre += (j < c) ? sj : 0.f;
  }
  // Matches reference f32 numerics: exp(tot) underflows to 0 -> denom = 1e-8
  const float invden = 1.0f / (__expf(tot) + 1e-8f);

  // in-quarter log values
  float la[4];
  float qsum = 0.f;
#pragma unroll
  for (int i = 0; i < 4; ++i) {
    const int t = c * C_LEN + q * 4 + i;
    la[i] = __logf(fmaxf(alpha[((size_t)t * B_DIM + b) * N_DIM + n], 1e-8f));
    qsum += la[i];
  }
  qs[q][n] = qsum;
  __syncthreads();

  float cum = pre;
#pragma unroll
  for (int q2 = 0; q2 < 3; ++q2)
    if (q2 < q) cum += qs[q2][n];
#pragma unroll
  for (int i = 0; i < 4; ++i) {
    const int t = c * C_LEN + q * 4 + i;
    const size_t idx = ((size_t)t * B_DIM + b) * N_DIM + n;
    cum += la[i];
    w[idx] = kk[idx] * __expf(cum) * invden;
  }
}

// ---------------------------------------------------------------------------
// K3: per-chunk partial sums psum[c] = sum_{t in chunk} v[t,b,d]*w[t,b,n].
// Grid = 64*8*4 = 2048 blocks x 256 thr. Burst-load 8 {v,w4} then reduce.
// ---------------------------------------------------------------------------
__global__ __launch_bounds__(256) void chunk_psum_kernel(
    const float* __restrict__ v, float* __restrict__ ws) {
  const int bid = blockIdx.x;
  const int dt = bid & 3;
  const int b  = (bid >> 2) & 7;
  const int c  = bid >> 5;
  const int tid = threadIdx.x;
  const int d  = dt * 16 + (tid >> 4);
  const int n0 = (tid & 15) * 4;

  const float* __restrict__ vp = v + (size_t)b * D_DIM + d;
  const float* __restrict__ wp = ws + WS_W + (size_t)b * N_DIM + n0;

  v4f acc = {0.f, 0.f, 0.f, 0.f};
#pragma unroll
  for (int bb = 0; bb < C_LEN / 8; ++bb) {
    float vv[8];
    v4f w4[8];
#pragma unroll
    for (int i = 0; i < 8; ++i) {
      const int t = c * C_LEN + bb * 8 + i;
      vv[i] = vp[(size_t)t * (B_DIM * D_DIM)];
      w4[i] = *(const v4f*)(wp + (size_t)t * (B_DIM * N_DIM));
    }
#pragma unroll
    for (int i = 0; i < 8; ++i) {
      acc.x = fmaf(vv[i], w4[i].x, acc.x);
      acc.y = fmaf(vv[i], w4[i].y, acc.y);
      acc.z = fmaf(vv[i], w4[i].z, acc.z);
      acc.w = fmaf(vv[i], w4[i].w, acc.w);
    }
  }
  *(v4f*)(ws + WS_PSUM + (((size_t)c * B_DIM + b) * D_DIM + d) * N_DIM + n0) = acc;
}

// ---------------------------------------------------------------------------
// K4: acc = sum_{j<c} psum[j] (independent 16B L2 gathers), then two 8-step
// batches: burst-load 8x{v,w4}, serial prefix chain + store burst.
// Grid = 2048 blocks x 256 thr; 1KB contiguous stores per wave per step.
// ---------------------------------------------------------------------------
__global__ __launch_bounds__(256) void scan_store_kernel(
    const float* __restrict__ v, const float* __restrict__ ws,
    float* __restrict__ out) {
  const int bid = blockIdx.x;
  const int dt = bid & 3;
  const int b  = (bid >> 2) & 7;
  const int c  = bid >> 5;
  const int tid = threadIdx.x;
  const int d  = dt * 16 + (tid >> 4);
  const int n0 = (tid & 15) * 4;

  const float* __restrict__ vp = v + (size_t)b * D_DIM + d;
  const float* __restrict__ wp = ws + WS_W + (size_t)b * N_DIM + n0;
  const float* __restrict__ pp = ws + WS_PSUM + ((size_t)b * D_DIM + d) * N_DIM + n0;

  v4f acc = {0.f, 0.f, 0.f, 0.f};
#pragma unroll 8
  for (int j = 0; j < c; ++j) {
    const v4f p = *(const v4f*)(pp + (size_t)j * SLAB);
    acc.x += p.x; acc.y += p.y; acc.z += p.z; acc.w += p.w;
  }

#pragma unroll
  for (int bb = 0; bb < C_LEN / 8; ++bb) {
    float vv[8];
    v4f w4[8];
#pragma unroll
    for (int i = 0; i < 8; ++i) {
      const int t = c * C_LEN + bb * 8 + i;
      vv[i] = vp[(size_t)t * (B_DIM * D_DIM)];
      w4[i] = *(const v4f*)(wp + (size_t)t * (B_DIM * N_DIM));
    }
#pragma unroll
    for (int i = 0; i < 8; ++i) {
      const int t = c * C_LEN + bb * 8 + i;
      acc.x = fmaf(vv[i], w4[i].x, acc.x);
      acc.y = fmaf(vv[i], w4[i].y, acc.y);
      acc.z = fmaf(vv[i], w4[i].z, acc.z);
      acc.w = fmaf(vv[i], w4[i].w, acc.w);
      *(v4f*)(out + (((size_t)t * B_DIM + b) * D_DIM + d) * N_DIM + n0) = acc;
    }
  }
}

// ---------------------------------------------------------------------------
extern "C" void kernel_launch(void* const* d_in, const int* in_sizes, int n_in,
                              void* d_out, int out_size, void* d_ws, size_t ws_size,
                              hipStream_t stream) {
  const float* v     = (const float*)d_in[0];
  const float* k     = (const float*)d_in[1];
  const float* alpha = (const float*)d_in[2];
  float* out = (float*)d_out;
  float* ws  = (float*)d_ws;  // uses ~10.6 MB

  float* lsum = ws + WS_LSUM;
  lsum_kernel<<<B_DIM * C_CHUNKS, 256, 0, stream>>>(alpha, lsum);
  w_emit_kernel<<<B_DIM * C_CHUNKS, 256, 0, stream>>>(alpha, k, lsum, ws + WS_W);
  chunk_psum_kernel<<<C_CHUNKS * B_DIM * 4, 256, 0, stream>>>(v, ws);
  scan_store_kernel<<<C_CHUNKS * B_DIM * 4, 256, 0, stream>>>(v, ws, out);
}